// Round 2
// baseline (451.219 us; speedup 1.0000x reference)
//
#include <hip/hip_runtime.h>

// CoPE2d: B=64, NH=16, Wh=Ww=16, N=256, C=64, NPOS=288
// query (BH,256,64) f32; attn_logits (BH,256,256) f32; pos_emb (64,288) f32;
// out (BH,256,256) f32. BH = 1024.
// One block per (bh, p): p = 16-row block. 320 threads (5 waves).

#define NPOS 288

// dst[i] += src[i+D] within 16-lane DPP rows, 0 beyond row end (bound_ctrl).
// row_shl:D = dpp_ctrl 0x100|D  (dst lane i reads src lane i+D).
template <int D>
__device__ __forceinline__ float suffix_step(float v) {
    int s = __builtin_amdgcn_update_dpp(0, __float_as_int(v), 0x100 | D, 0xF, 0xF, true);
    return v + __int_as_float(s);
}

__global__ __launch_bounds__(320, 3) void cope2d_kernel(
    const float* __restrict__ query,
    const float* __restrict__ attn_logits,
    const float* __restrict__ pos_emb,
    float* __restrict__ out)
{
    __shared__ float Ltab[16 * NPOS];   // 18432 B

    const int tid = threadIdx.x;
    const int blk = blockIdx.x;
    const int bh  = blk >> 4;
    const int p   = blk & 15;
    const long rowbase = (long)bh * 256 + p * 16;

    // ---------------- GEMM: Ltab[i][t] = sum_c q[n0+i][c] * P[c][t] ----------
    // 16 accumulators per thread; pos_emb column element loaded ONCE per c;
    // q reads are wave-uniform -> expect s_load scalarization.
    if (tid < NPOS) {
        const float* qbase = query + rowbase * 64;  // uniform per block
        float acc[16];
        #pragma unroll
        for (int i = 0; i < 16; ++i) acc[i] = 0.f;

        #pragma unroll 8
        for (int c = 0; c < 64; ++c) {
            float pcv = pos_emb[c * NPOS + tid];    // coalesced, loaded once
            #pragma unroll
            for (int i = 0; i < 16; ++i)
                acc[i] = fmaf(qbase[i * 64 + c], pcv, acc[i]);
        }
        #pragma unroll
        for (int i = 0; i < 16; ++i)
            Ltab[i * NPOS + tid] = acc[i];
    }
    __syncthreads();

    // ---------------- gates -> pos_h/pos_w -> gather+lerp -> out -------------
    if (tid < 256) {
        const int j = tid;
        const long gbase = rowbase * 256;

        float acc_h = 0.f;                  // suffix over rows (pos_h), serial
        #pragma unroll
        for (int i = 15; i >= 0; --i) {
            float x = attn_logits[gbase + (long)i * 256 + j];  // coalesced
            float g = 1.0f / (1.0f + __expf(-x));              // sigmoid
            acc_h += g;

            // inclusive suffix scan within aligned 16-lane groups via DPP
            float pw = suffix_step<8>(suffix_step<4>(suffix_step<2>(suffix_step<1>(g))));

            float pos = acc_h * 16.0f + pw;
            pos = fminf(pos, 287.0f);       // never binds (pos < 272)
            float pf = floorf(pos);
            int   fi = (int)pf;
            float w  = pos - pf;

            const float* Lrow = Ltab + i * NPOS;
            float lf = Lrow[fi];
            float lc = Lrow[fi + 1];
            out[gbase + (long)i * 256 + j] = lf + w * (lc - lf);
        }
    }
}

extern "C" void kernel_launch(void* const* d_in, const int* in_sizes, int n_in,
                              void* d_out, int out_size, void* d_ws, size_t ws_size,
                              hipStream_t stream) {
    const float* query       = (const float*)d_in[0];
    const float* attn_logits = (const float*)d_in[1];
    const float* pos_emb     = (const float*)d_in[2];
    float* outp = (float*)d_out;

    cope2d_kernel<<<16384, 320, 0, stream>>>(query, attn_logits, pos_emb, outp);
}

// Round 3
// 388.955 us; speedup vs baseline: 1.1601x; 1.1601x over previous
//
#include <hip/hip_runtime.h>

// CoPE2d: B=64, NH=16, Wh=Ww=16, N=256, C=64, NPOS=288
// query (BH,256,64) f32; attn_logits (BH,256,256) f32; pos_emb (64,288) f32;
// out (BH,256,256) f32. BH = 1024.
// One block per (bh, p): p = 16-row block. 320 threads (5 waves).

#define NPOS 288

// dst[i] = src[i] + src[i+D] within 16-lane DPP rows, 0 beyond row end.
template <int D>
__device__ __forceinline__ float suffix_step(float v) {
    int s = __builtin_amdgcn_update_dpp(0, __float_as_int(v), 0x100 | D, 0xF, 0xF, true);
    return v + __int_as_float(s);
}

__global__ __launch_bounds__(320, 3) void cope2d_kernel(
    const float* __restrict__ query,
    const float* __restrict__ attn_logits,
    const float* __restrict__ pos_emb,
    float* __restrict__ out)
{
    __shared__ float Ltab[16 * NPOS];   // 18432 B

    const int tid = threadIdx.x;
    const int blk = blockIdx.x;
    const int bh  = blk >> 4;
    const int p   = blk & 15;
    const long rowbase = (long)bh * 256 + p * 16;
    const long gbase   = rowbase * 256;

    // -------- issue ALL gate loads first: HBM latency hides under the GEMM --
    float g[16];
    if (tid < 256) {
        #pragma unroll
        for (int i = 0; i < 16; ++i)
            g[i] = attn_logits[gbase + (long)i * 256 + tid];   // coalesced
    }

    // ---------------- GEMM: Ltab[i][t] = sum_c q[n0+i][c] * P[c][t] ----------
    if (tid < NPOS) {
        const float* qbase = query + rowbase * 64;  // wave-uniform -> s_load
        float acc[16];
        #pragma unroll
        for (int i = 0; i < 16; ++i) acc[i] = 0.f;

        #pragma unroll 8
        for (int c = 0; c < 64; ++c) {
            float pcv = pos_emb[c * NPOS + tid];    // coalesced, loaded once
            #pragma unroll
            for (int i = 0; i < 16; ++i)
                acc[i] = fmaf(qbase[i * 64 + c], pcv, acc[i]);
        }
        #pragma unroll
        for (int i = 0; i < 16; ++i)
            Ltab[i * NPOS + tid] = acc[i];
    }
    __syncthreads();

    // ------------- batched gates -> pos -> gather+lerp -> out ---------------
    if (tid < 256) {
        // independent sigmoids
        #pragma unroll
        for (int i = 0; i < 16; ++i)
            g[i] = 1.0f / (1.0f + __expf(-g[i]));

        // pos_h: in-register suffix over this thread's own 16 rows
        float sfx[16];
        float run = 0.f;
        #pragma unroll
        for (int i = 15; i >= 0; --i) { run += g[i]; sfx[i] = run; }

        // two batches of 8 rows: scans, gathers, lerps all batched (MLP)
        #pragma unroll
        for (int half = 0; half < 2; ++half) {
            const int i0 = half * 8;
            float w8[8]; int fi8[8];
            #pragma unroll
            for (int k = 0; k < 8; ++k) {
                const int i = i0 + k;
                // pos_w: inclusive suffix scan within aligned 16-lane groups
                float pw = suffix_step<8>(suffix_step<4>(suffix_step<2>(suffix_step<1>(g[i]))));
                float pos = fminf(sfx[i] * 16.0f + pw, 287.0f);
                float pf = floorf(pos);
                fi8[k] = (int)pf;
                w8[k]  = pos - pf;
            }
            float lf8[8], lc8[8];
            #pragma unroll
            for (int k = 0; k < 8; ++k) {
                const float* Lr = Ltab + (i0 + k) * NPOS;
                lf8[k] = Lr[fi8[k]];
                lc8[k] = Lr[fi8[k] + 1];
            }
            #pragma unroll
            for (int k = 0; k < 8; ++k)
                out[gbase + (long)(i0 + k) * 256 + tid] =
                    lf8[k] + w8[k] * (lc8[k] - lf8[k]);
        }
    }
}

extern "C" void kernel_launch(void* const* d_in, const int* in_sizes, int n_in,
                              void* d_out, int out_size, void* d_ws, size_t ws_size,
                              hipStream_t stream) {
    const float* query       = (const float*)d_in[0];
    const float* attn_logits = (const float*)d_in[1];
    const float* pos_emb     = (const float*)d_in[2];
    float* outp = (float*)d_out;

    cope2d_kernel<<<16384, 320, 0, stream>>>(query, attn_logits, pos_emb, outp);
}

// Round 4
// 137.647 us; speedup vs baseline: 3.2781x; 2.8257x over previous
//
#include <hip/hip_runtime.h>

// CoPE2d: B=64, NH=16, Wh=Ww=16, N=256, C=64, NPOS=288, BH=1024
// query (BH,256,64) f32; attn_logits (BH,256,256) f32; pos_emb (64,288) f32;
// out (BH,256,256) f32.
// One block per (bh, p): 16-row block, 256 threads (4 waves).

#define NPOS 288
#define NT   18          // npos tiles of 16
#define LTS  288         // Ltab row stride (floats)

typedef __attribute__((ext_vector_type(8))) short bf16x8;
typedef __attribute__((ext_vector_type(4))) float f32x4;

__device__ __forceinline__ short f2bf(float f) {   // RNE f32 -> bf16 bits
    unsigned u = __float_as_uint(f);
    u += 0x7FFF + ((u >> 16) & 1);
    return (short)(u >> 16);
}

// dst[i] = src[i] + src[i+D] within 16-lane DPP rows, 0 beyond row end.
template <int D>
__device__ __forceinline__ float suffix_step(float v) {
    int s = __builtin_amdgcn_update_dpp(0, __float_as_int(v), 0x100 | D, 0xF, 0xF, true);
    return v + __int_as_float(s);
}

// ---- prep: pos_emb (64x288 f32) -> bf16 B-fragments in ws ------------------
// frag f = (t*2+s)*64 + lane holds 8 bf16: B[k][col], col=16t+(l&15),
// k = 32s + (l>>4)*8 + j   (mfma_f32_16x16x32_bf16 B-operand layout)
__global__ void prep_kernel(const float* __restrict__ pos_emb,
                            short* __restrict__ wsb) {
    int idx = blockIdx.x * blockDim.x + threadIdx.x;   // 0 .. NT*2*64
    if (idx >= NT * 2 * 64) return;
    int l = idx & 63;
    int s = (idx >> 6) & 1;
    int t = idx >> 7;
    int col = t * 16 + (l & 15);
    int k0  = s * 32 + (l >> 4) * 8;
    short* dst = wsb + idx * 8;
    #pragma unroll
    for (int j = 0; j < 8; ++j)
        dst[j] = f2bf(pos_emb[(k0 + j) * NPOS + col]);
}

__global__ __launch_bounds__(256, 6) void cope2d_kernel(
    const float* __restrict__ query,
    const float* __restrict__ attn_logits,
    const bf16x8* __restrict__ wsb8,     // precomputed B fragments
    float* __restrict__ out)
{
    __shared__ float Ltab[16 * LTS];     // 18432 B

    const int tid  = threadIdx.x;
    const int lane = tid & 63;
    const int wave = tid >> 6;
    const int blk  = blockIdx.x;
    const int bh   = blk >> 4;
    const int p    = blk & 15;
    const long rowbase = (long)bh * 256 + p * 16;
    const long gbase   = rowbase * 256;

    // ---- A fragments: q rows -> bf16 (row = lane&15, k = (lane>>4)*8+j) ----
    const float* qptr = query + (rowbase + (lane & 15)) * 64 + (lane >> 4) * 8;
    bf16x8 A[2];
    #pragma unroll
    for (int s = 0; s < 2; ++s) {
        f32x4 lo = *(const f32x4*)(qptr + s * 32);
        f32x4 hi = *(const f32x4*)(qptr + s * 32 + 4);
        #pragma unroll
        for (int j = 0; j < 4; ++j) { A[s][j] = f2bf(lo[j]); A[s][4 + j] = f2bf(hi[j]); }
    }

    // ---- early gate loads: HBM latency hides under GEMM --------------------
    float g[16];
    #pragma unroll
    for (int i = 0; i < 16; ++i)
        g[i] = attn_logits[gbase + (long)i * 256 + tid];   // coalesced

    // ---- MFMA GEMM: Ltab = q(16x64) @ P(64x288), tiles round-robin by wave --
    for (int t = wave; t < NT; t += 4) {
        f32x4 c = {0.f, 0.f, 0.f, 0.f};
        c = __builtin_amdgcn_mfma_f32_16x16x32_bf16(A[0], wsb8[(t * 2 + 0) * 64 + lane], c, 0, 0, 0);
        c = __builtin_amdgcn_mfma_f32_16x16x32_bf16(A[1], wsb8[(t * 2 + 1) * 64 + lane], c, 0, 0, 0);
        const int col = t * 16 + (lane & 15);
        const int r0  = (lane >> 4) * 4;
        #pragma unroll
        for (int r = 0; r < 4; ++r)
            Ltab[(r0 + r) * LTS + col] = c[r];
    }
    __syncthreads();

    // ---- gates -> pos -> gather+lerp -> out (batched) ----------------------
    {
        #pragma unroll
        for (int i = 0; i < 16; ++i)
            g[i] = 1.0f / (1.0f + __expf(-g[i]));          // sigmoid

        float sfx[16];                                      // pos_h suffix (own regs)
        float run = 0.f;
        #pragma unroll
        for (int i = 15; i >= 0; --i) { run += g[i]; sfx[i] = run; }

        #pragma unroll
        for (int half = 0; half < 2; ++half) {
            const int i0 = half * 8;
            float w8[8]; int fi8[8];
            #pragma unroll
            for (int k = 0; k < 8; ++k) {
                const int i = i0 + k;
                float pw = suffix_step<8>(suffix_step<4>(suffix_step<2>(suffix_step<1>(g[i]))));
                float pos = fminf(sfx[i] * 16.0f + pw, 287.0f);
                float pf = floorf(pos);
                fi8[k] = (int)pf;
                w8[k]  = pos - pf;
            }
            float lf8[8], lc8[8];
            #pragma unroll
            for (int k = 0; k < 8; ++k) {
                const float* Lr = Ltab + (i0 + k) * LTS;
                lf8[k] = Lr[fi8[k]];
                lc8[k] = Lr[fi8[k] + 1];
            }
            #pragma unroll
            for (int k = 0; k < 8; ++k)
                out[gbase + (long)(i0 + k) * 256 + tid] =
                    lf8[k] + w8[k] * (lc8[k] - lf8[k]);
        }
    }
}

extern "C" void kernel_launch(void* const* d_in, const int* in_sizes, int n_in,
                              void* d_out, int out_size, void* d_ws, size_t ws_size,
                              hipStream_t stream) {
    const float* query       = (const float*)d_in[0];
    const float* attn_logits = (const float*)d_in[1];
    const float* pos_emb     = (const float*)d_in[2];
    float* outp = (float*)d_out;
    short* wsb  = (short*)d_ws;          // NT*2*64*8 bf16 = 36 KB

    prep_kernel<<<9, 256, 0, stream>>>(pos_emb, wsb);
    cope2d_kernel<<<16384, 256, 0, stream>>>(query, attn_logits,
                                             (const bf16x8*)d_ws, outp);
}

// Round 5
// 135.355 us; speedup vs baseline: 3.3336x; 1.0169x over previous
//
#include <hip/hip_runtime.h>

// CoPE2d: B=64, NH=16, Wh=Ww=16, N=256, C=64, NPOS=288, BH=1024
// query (BH,256,64) f32; attn_logits (BH,256,256) f32; pos_emb (64,288) f32;
// out (BH,256,256) f32.
// One block per (bh, p): 16-row block, 256 threads (4 waves), 6 blocks/CU.

#define NPOS 288
#define NT   18          // npos tiles of 16
#define LTS2 292         // bf16 Ltab row stride (u16 elements)

typedef __attribute__((ext_vector_type(8))) short bf16x8;
typedef __attribute__((ext_vector_type(4))) float f32x4;

__device__ __forceinline__ unsigned short f2bf(float f) {   // RNE f32->bf16
    unsigned u = __float_as_uint(f);
    u += 0x7FFF + ((u >> 16) & 1);
    return (unsigned short)(u >> 16);
}
__device__ __forceinline__ float bf2f(unsigned short b) {
    return __uint_as_float(((unsigned)b) << 16);
}

// dst[i] = src[i] + src[i+D] within 16-lane DPP rows, 0 beyond row end.
template <int D>
__device__ __forceinline__ float suffix_step(float v) {
    int s = __builtin_amdgcn_update_dpp(0, __float_as_int(v), 0x100 | D, 0xF, 0xF, true);
    return v + __int_as_float(s);
}

// async global->LDS, 16B per lane; lds dest = uniform base + lane*16
#define GLDS(gsrc, ldst) __builtin_amdgcn_global_load_lds(                      \
    (const __attribute__((address_space(1))) void*)(gsrc),                      \
    (__attribute__((address_space(3))) void*)(ldst), 16, 0, 0)

// ---- prep: pos_emb (64x288 f32) -> bf16 B-fragments in ws ------------------
__global__ void prep_kernel(const float* __restrict__ pos_emb,
                            short* __restrict__ wsb) {
    int idx = blockIdx.x * blockDim.x + threadIdx.x;   // 0 .. NT*2*64
    if (idx >= NT * 2 * 64) return;
    int l = idx & 63;
    int s = (idx >> 6) & 1;
    int t = idx >> 7;
    int col = t * 16 + (l & 15);
    int k0  = s * 32 + (l >> 4) * 8;
    short* dst = wsb + idx * 8;
    #pragma unroll
    for (int j = 0; j < 8; ++j)
        dst[j] = (short)f2bf(pos_emb[(k0 + j) * NPOS + col]);
}

__global__ __launch_bounds__(256, 6) void cope2d_kernel(
    const float* __restrict__ query,
    const float* __restrict__ attn_logits,
    const bf16x8* __restrict__ wsb8,
    float* __restrict__ out)
{
    __shared__ float          Gl[16 * 256];   // 16384 B raw gate logits
    __shared__ unsigned short Lb[16 * LTS2];  //  9344 B bf16 logits_int table

    const int tid  = threadIdx.x;
    const int lane = tid & 63;
    const int wave = tid >> 6;
    const int blk  = blockIdx.x;
    const int bh   = blk >> 4;
    const int p    = blk & 15;
    const long rowbase = (long)bh * 256 + p * 16;
    const long gbase   = rowbase * 256;

    // ---- FIRST: async DMA all 16 gate rows into LDS (no VGPRs held) --------
    {
        const float* src = attn_logits + gbase + (long)(wave * 4) * 256 + lane * 4;
        float* dst = &Gl[(wave * 4) * 256];
        #pragma unroll
        for (int r = 0; r < 4; ++r)
            GLDS(src + r * 256, dst + r * 256);
    }

    // ---- A fragments: q rows -> bf16 (row = lane&15, k = (lane>>4)*8+j) ----
    const float* qptr = query + (rowbase + (lane & 15)) * 64 + (lane >> 4) * 8;
    bf16x8 A[2];
    #pragma unroll
    for (int s = 0; s < 2; ++s) {
        f32x4 lo = *(const f32x4*)(qptr + s * 32);
        f32x4 hi = *(const f32x4*)(qptr + s * 32 + 4);
        #pragma unroll
        for (int j = 0; j < 4; ++j) { A[s][j] = (short)f2bf(lo[j]); A[s][4 + j] = (short)f2bf(hi[j]); }
    }

    // ---- batch-load ALL B fragments for this wave's tiles, then MFMA -------
    bf16x8 Bf[5][2];
    #pragma unroll
    for (int u = 0; u < 5; ++u) {
        int t = wave + 4 * u;
        if (t < NT) {
            Bf[u][0] = wsb8[(t * 2 + 0) * 64 + lane];
            Bf[u][1] = wsb8[(t * 2 + 1) * 64 + lane];
        }
    }
    #pragma unroll
    for (int u = 0; u < 5; ++u) {
        int t = wave + 4 * u;
        if (t < NT) {
            f32x4 c = {0.f, 0.f, 0.f, 0.f};
            c = __builtin_amdgcn_mfma_f32_16x16x32_bf16(A[0], Bf[u][0], c, 0, 0, 0);
            c = __builtin_amdgcn_mfma_f32_16x16x32_bf16(A[1], Bf[u][1], c, 0, 0, 0);
            const int col = t * 16 + (lane & 15);
            const int r0  = (lane >> 4) * 4;
            #pragma unroll
            for (int r = 0; r < 4; ++r)
                Lb[(r0 + r) * LTS2 + col] = f2bf(c[r]);
        }
    }

    __syncthreads();   // drains vmcnt(0): gate DMA + lgkm: Lb writes

    // ---- gates -> pos -> gather+lerp -> out (batched) ----------------------
    {
        float g[16];
        #pragma unroll
        for (int i = 0; i < 16; ++i)
            g[i] = Gl[i * 256 + tid];                      // conflict-free ds_read
        #pragma unroll
        for (int i = 0; i < 16; ++i)
            g[i] = 1.0f / (1.0f + __expf(-g[i]));          // sigmoid

        float sfx[16];                                      // pos_h suffix
        float run = 0.f;
        #pragma unroll
        for (int i = 15; i >= 0; --i) { run += g[i]; sfx[i] = run; }

        #pragma unroll
        for (int half = 0; half < 2; ++half) {
            const int i0 = half * 8;
            float w8[8]; int fi8[8];
            #pragma unroll
            for (int k = 0; k < 8; ++k) {
                const int i = i0 + k;
                float pw = suffix_step<8>(suffix_step<4>(suffix_step<2>(suffix_step<1>(g[i]))));
                float pos = fminf(sfx[i] * 16.0f + pw, 287.0f);
                float pf = floorf(pos);
                fi8[k] = (int)pf;
                w8[k]  = pos - pf;
            }
            float lf8[8], lc8[8];
            #pragma unroll
            for (int k = 0; k < 8; ++k) {
                const unsigned short* Lr = Lb + (i0 + k) * LTS2;
                lf8[k] = bf2f(Lr[fi8[k]]);
                lc8[k] = bf2f(Lr[fi8[k] + 1]);
            }
            #pragma unroll
            for (int k = 0; k < 8; ++k)
                out[gbase + (long)(i0 + k) * 256 + tid] =
                    lf8[k] + w8[k] * (lc8[k] - lf8[k]);
        }
    }
}

extern "C" void kernel_launch(void* const* d_in, const int* in_sizes, int n_in,
                              void* d_out, int out_size, void* d_ws, size_t ws_size,
                              hipStream_t stream) {
    const float* query       = (const float*)d_in[0];
    const float* attn_logits = (const float*)d_in[1];
    const float* pos_emb     = (const float*)d_in[2];
    float* outp = (float*)d_out;
    short* wsb  = (short*)d_ws;          // NT*2*64*8 bf16 = 36 KB

    prep_kernel<<<9, 256, 0, stream>>>(pos_emb, wsb);
    cope2d_kernel<<<16384, 256, 0, stream>>>(query, attn_logits,
                                             (const bf16x8*)d_ws, outp);
}